// Round 2
// baseline (855.992 us; speedup 1.0000x reference)
//
#include <hip/hip_runtime.h>
#include <hip/hip_bf16.h>
#include <cstddef>
#include <cstdint>

// AttentionBlock fused implementation for MI355X (gfx950).
//
// Pipeline (all on `stream`):
//   0. memset colw/res accumulators (ws)
//   1. proj_kernel: Q/K/V = (q|k|v) @ W.T  -> bf16, MFMA 16x16x32, 64x64 tiles
//   2. bias_conv_kernel: attn_bias f32 -> bf16
//   3. res_sum_kernel: res = q.sum(axis=1) (f32, atomics)
//   4. attn_kernel: per (b, q-tile, h): S^T = K_h @ Q_tile^T via MFMA,
//      softmax WITHOUT max-subtraction (energies bounded ~|1|), two passes
//      (pass1 rowsums, pass2 normalize + float4 NT store + colw column sums)
//   5. xs_kernel: xs[b,h,d] = sum_k colw[b,h,k] * V[b,k,h,d]
//   6. final_kernel: out = mish(BN(xs @ W1.T + b1)) + res

typedef __attribute__((ext_vector_type(8))) short short8;
typedef __attribute__((ext_vector_type(4))) float f32x4;

namespace {
constexpr int kB = 16;
constexpr int kS = 1024;   // SQ == SK
constexpr int kH = 256;
constexpr int kNH = 8;
constexpr int kM = kB * kS;  // 16384 rows for projections

// workspace layout (bytes)
constexpr size_t SZ_PROJ = (size_t)kM * kH * 2;         // 8 MiB (bf16)
constexpr size_t OFF_QBF = 0;
constexpr size_t OFF_KBF = OFF_QBF + SZ_PROJ;
constexpr size_t OFF_VBF = OFF_KBF + SZ_PROJ;
constexpr size_t OFF_BIAS = OFF_VBF + SZ_PROJ;          // bf16 bias, 16 MiB
constexpr size_t SZ_BIAS = (size_t)kNH * kS * kS * 2;
constexpr size_t OFF_COLW = OFF_BIAS + SZ_BIAS;         // f32 [B,NH,SK]
constexpr size_t SZ_COLW = (size_t)kB * kNH * kS * 4;
constexpr size_t OFF_RES = OFF_COLW + SZ_COLW;          // f32 [B,H]
constexpr size_t SZ_RES = (size_t)kB * kH * 4;
constexpr size_t OFF_XS = OFF_RES + SZ_RES;             // f32 [B,H]
}  // namespace

__device__ __forceinline__ unsigned short f2bf(float f) {
  __hip_bfloat16 h = __float2bfloat16(f);
  unsigned short u;
  __builtin_memcpy(&u, &h, 2);
  return u;
}
__device__ __forceinline__ float bf2f(unsigned short u) {
  return __uint_as_float(((unsigned int)u) << 16);
}

// ---------------------------------------------------------------------------
// Projection: D[row][j] = sum_c X[row][c] * W[j][c], output bf16.
// grid (kM/64, kH/64, 3), block 256 (4 waves). 64x64 tile, K=256 staged whole.
// LDS tiles are bf16 with byte-XOR swizzle ((row&7)<<4) for conflict-free
// ds_read_b128 fragment reads (rows are 512B apart).
// ---------------------------------------------------------------------------
__global__ __launch_bounds__(256) void proj_kernel(
    const float* __restrict__ qin, const float* __restrict__ kin,
    const float* __restrict__ vin, const float* __restrict__ wq,
    const float* __restrict__ wk, const float* __restrict__ wv,
    unsigned short* __restrict__ Qbf, unsigned short* __restrict__ Kbf,
    unsigned short* __restrict__ Vbf) {
  __shared__ unsigned char smem[65536];  // [0,32K): X tile, [32K,64K): W tile
  const int z = blockIdx.z;
  const float* __restrict__ X = (z == 0) ? qin : ((z == 1) ? kin : vin);
  const float* __restrict__ W = (z == 0) ? wq : ((z == 1) ? wk : wv);
  unsigned short* __restrict__ D = (z == 0) ? Qbf : ((z == 1) ? Kbf : Vbf);
  const int tid = threadIdx.x;
  const int rb = blockIdx.x << 6;  // row base in [0,16384)
  const int jb = blockIdx.y << 6;  // out-col base in [0,256)

  for (int i = tid; i < 64 * 64; i += 256) {
    const int r = i >> 6, c4 = i & 63;  // row, float4-chunk
    const float4 xv =
        *reinterpret_cast<const float4*>(X + (size_t)(rb + r) * kH + c4 * 4);
    const float4 wv4 =
        *reinterpret_cast<const float4*>(W + (size_t)(jb + r) * kH + c4 * 4);
    const ushort4 px =
        make_ushort4(f2bf(xv.x), f2bf(xv.y), f2bf(xv.z), f2bf(xv.w));
    const ushort4 pw =
        make_ushort4(f2bf(wv4.x), f2bf(wv4.y), f2bf(wv4.z), f2bf(wv4.w));
    const unsigned a = (unsigned)(r * 512 + c4 * 8) ^ (unsigned)((r & 7) << 4);
    *reinterpret_cast<ushort4*>(smem + a) = px;
    *reinterpret_cast<ushort4*>(smem + 32768 + a) = pw;
  }
  __syncthreads();

  const int w = tid >> 6, lane = tid & 63;
  const int l15 = lane & 15, lg = lane >> 4;
  const unsigned sw = (unsigned)((l15 & 7) << 4);
  f32x4 acc[4];
#pragma unroll
  for (int m = 0; m < 4; ++m) acc[m] = (f32x4){0.f, 0.f, 0.f, 0.f};

#pragma unroll
  for (int k0 = 0; k0 < 256; k0 += 32) {
    // B fragment: W row (jb + w*16 + l15), cols k0 + lg*8 .. +8
    const unsigned bofs =
        ((unsigned)((w * 16 + l15) * 512 + k0 * 2 + lg * 16)) ^ sw;
    const short8 bf = *reinterpret_cast<const short8*>(smem + 32768 + bofs);
#pragma unroll
    for (int m = 0; m < 4; ++m) {
      const unsigned aofs =
          ((unsigned)(m * 8192 + l15 * 512 + k0 * 2 + lg * 16)) ^ sw;
      const short8 af = *reinterpret_cast<const short8*>(smem + aofs);
      acc[m] = __builtin_amdgcn_mfma_f32_16x16x32_bf16(af, bf, acc[m], 0, 0, 0);
    }
  }
  // D layout: col = lane&15, row = (lane>>4)*4 + reg  (within 16x16 tile m)
#pragma unroll
  for (int m = 0; m < 4; ++m) {
#pragma unroll
    for (int r = 0; r < 4; ++r) {
      const int row = rb + m * 16 + lg * 4 + r;
      D[(size_t)row * kH + jb + w * 16 + l15] = f2bf(acc[m][r]);
    }
  }
}

// ---------------------------------------------------------------------------
// Bias f32 -> bf16 (8M elements)
// ---------------------------------------------------------------------------
__global__ __launch_bounds__(256) void bias_conv_kernel(
    const float* __restrict__ bias, unsigned short* __restrict__ biasbf) {
  const size_t i = ((size_t)blockIdx.x * 256 + threadIdx.x) * 4;
  const float4 v = *reinterpret_cast<const float4*>(bias + i);
  const ushort4 o = make_ushort4(f2bf(v.x), f2bf(v.y), f2bf(v.z), f2bf(v.w));
  *reinterpret_cast<ushort4*>(biasbf + i) = o;
}

// ---------------------------------------------------------------------------
// res = q.sum(axis=1): grid B*8 (seq chunks of 128), atomics into zeroed res
// ---------------------------------------------------------------------------
__global__ __launch_bounds__(256) void res_sum_kernel(
    const float* __restrict__ qin, float* __restrict__ res) {
  const int b = blockIdx.x >> 3;
  const int ch = blockIdx.x & 7;
  const int j = threadIdx.x;
  const float* p = qin + ((size_t)b * kS + ch * 128) * kH + j;
  float s = 0.f;
#pragma unroll 8
  for (int i = 0; i < 128; ++i) s += p[(size_t)i * kH];
  atomicAdd(&res[b * kH + j], s);
}

// ---------------------------------------------------------------------------
// Attention: grid (b=16, qtile=16, h=8), block 256 = 4 waves.
// Each wave owns 16 q-cols (B operand); loops 64 k-tiles (A = K fragments from
// fragment-linear LDS). S^T orientation -> C reg r = consecutive k  => float4
// stores. No-max softmax: E = exp2(S*c1 + bias*c2). Pass1 rowsums, pass2
// writes + column sums (for the pooled PV).
// ---------------------------------------------------------------------------
__global__ __launch_bounds__(256) void attn_kernel(
    const unsigned short* __restrict__ Qbf, const unsigned short* __restrict__ Kbf,
    const unsigned short* __restrict__ biasbf, float* __restrict__ attn_out,
    float* __restrict__ colw) {
  __shared__ unsigned char kmem[65536];   // K_h fragment-linear: [64 mtiles][64 lanes][16B]
  __shared__ float ldscw[4][1024];        // per-wave column sums
  const int b = blockIdx.x, qt = blockIdx.y, h = blockIdx.z;
  const int tid = threadIdx.x, w = tid >> 6, lane = tid & 63;
  const int l15 = lane & 15, lg = lane >> 4;

  // stage K_h (1024x32 bf16) into fragment order
  for (int i = tid; i < 4096; i += 256) {
    const int m = i >> 6, l = i & 63;
    const size_t gofs =
        ((size_t)(b * kS + m * 16 + (l & 15))) * kH + h * 32 + (l >> 4) * 8;
    *reinterpret_cast<short8*>(kmem + i * 16) =
        *reinterpret_cast<const short8*>(Kbf + gofs);
  }
  for (int i = tid; i < 4096; i += 256) reinterpret_cast<float*>(ldscw)[i] = 0.f;

  const int qcol = qt * 64 + w * 16 + l15;
  const short8 qf = *reinterpret_cast<const short8*>(
      Qbf + ((size_t)(b * kS + qcol)) * kH + h * 32 + lg * 8);
  __syncthreads();

  const unsigned short* __restrict__ bptr =
      biasbf + ((size_t)(h * kS + qcol)) * kS + lg * 4;
  const float C2 = 1.44269504f;               // log2(e)
  const float C1 = C2 * 0.17677669529663689f; // log2(e)/sqrt(32)

  // ---- pass 1: row sums (no max subtraction; |energy| < ~1) ----
  float rs = 0.f;
#pragma unroll 4
  for (int m = 0; m < 64; ++m) {
    const short8 kf =
        *reinterpret_cast<const short8*>(kmem + (m * 64 + lane) * 16);
    f32x4 acc = {0.f, 0.f, 0.f, 0.f};
    acc = __builtin_amdgcn_mfma_f32_16x16x32_bf16(kf, qf, acc, 0, 0, 0);
    const ushort4 bb = *reinterpret_cast<const ushort4*>(bptr + m * 16);
    rs += exp2f(acc[0] * C1 + bf2f(bb.x) * C2);
    rs += exp2f(acc[1] * C1 + bf2f(bb.y) * C2);
    rs += exp2f(acc[2] * C1 + bf2f(bb.z) * C2);
    rs += exp2f(acc[3] * C1 + bf2f(bb.w) * C2);
  }
  rs += __shfl_xor(rs, 16);
  rs += __shfl_xor(rs, 32);
  const float inv = 1.0f / rs;

  // ---- pass 2: normalize, write, column sums ----
  float* __restrict__ aoutq =
      attn_out + ((size_t)((b * kNH + h) * kS + qcol)) * kS;
#pragma unroll 2
  for (int m = 0; m < 64; ++m) {
    const short8 kf =
        *reinterpret_cast<const short8*>(kmem + (m * 64 + lane) * 16);
    f32x4 acc = {0.f, 0.f, 0.f, 0.f};
    acc = __builtin_amdgcn_mfma_f32_16x16x32_bf16(kf, qf, acc, 0, 0, 0);
    const ushort4 bb = *reinterpret_cast<const ushort4*>(bptr + m * 16);
    f32x4 p;
    p.x = exp2f(acc[0] * C1 + bf2f(bb.x) * C2) * inv;
    p.y = exp2f(acc[1] * C1 + bf2f(bb.y) * C2) * inv;
    p.z = exp2f(acc[2] * C1 + bf2f(bb.z) * C2) * inv;
    p.w = exp2f(acc[3] * C1 + bf2f(bb.w) * C2) * inv;
    __builtin_nontemporal_store(
        p, reinterpret_cast<f32x4*>(aoutq + m * 16 + lg * 4));
    // column sums: reduce each reg over the 16 q-lanes of this group
    float s0 = p.x, s1 = p.y, s2 = p.z, s3 = p.w;
#pragma unroll
    for (int dd = 1; dd < 16; dd <<= 1) {
      s0 += __shfl_xor(s0, dd);
      s1 += __shfl_xor(s1, dd);
      s2 += __shfl_xor(s2, dd);
      s3 += __shfl_xor(s3, dd);
    }
    if (l15 == 0) {
      float* cwp = &ldscw[w][m * 16 + lg * 4];
      cwp[0] += s0;
      cwp[1] += s1;
      cwp[2] += s2;
      cwp[3] += s3;
    }
  }
  __syncthreads();
  const int bh = b * kNH + h;
  for (int i = tid; i < 1024; i += 256) {
    atomicAdd(&colw[(size_t)bh * kS + i],
              ldscw[0][i] + ldscw[1][i] + ldscw[2][i] + ldscw[3][i]);
  }
}

// ---------------------------------------------------------------------------
// xs[b, h*32+d] = sum_k colw[b,h,k] * V[b,k,h*32+d]
// ---------------------------------------------------------------------------
__global__ __launch_bounds__(256) void xs_kernel(
    const float* __restrict__ colw, const unsigned short* __restrict__ Vbf,
    float* __restrict__ xs) {
  __shared__ float red[256];
  const int bh = blockIdx.x;
  const int b = bh >> 3, h = bh & 7;
  const int t = threadIdx.x;
  const int d = t & 31, ch = t >> 5;  // 8 chunks x 128 k
  const float* cw = colw + (size_t)bh * kS;
  const unsigned short* vp =
      Vbf + ((size_t)b * kS + ch * 128) * kH + h * 32 + d;
  float s = 0.f;
#pragma unroll 4
  for (int i = 0; i < 128; ++i) s += cw[ch * 128 + i] * bf2f(vp[(size_t)i * kH]);
  red[t] = s;
  __syncthreads();
  if (t < 32) {
    float tot = 0.f;
#pragma unroll
    for (int c = 0; c < 8; ++c) tot += red[c * 32 + t];
    xs[b * kH + h * 32 + t] = tot;
  }
}

// ---------------------------------------------------------------------------
// out = mish(BN(xs @ W1.T + b1)) + res
// ---------------------------------------------------------------------------
__global__ __launch_bounds__(256) void final_kernel(
    const float* __restrict__ xs, const float* __restrict__ res,
    const float* __restrict__ W1, const float* __restrict__ b1,
    const float* __restrict__ gamma, const float* __restrict__ beta,
    const float* __restrict__ rmean, const float* __restrict__ rvar,
    float* __restrict__ out) {
  __shared__ float sx[kH];
  const int b = blockIdx.x, j = threadIdx.x;
  sx[j] = xs[b * kH + j];
  __syncthreads();
  float acc = b1[j];
  const float* wrow = W1 + (size_t)j * kH;
#pragma unroll 8
  for (int c = 0; c < kH; c += 4) {
    const float4 wv = *reinterpret_cast<const float4*>(wrow + c);
    acc += sx[c] * wv.x + sx[c + 1] * wv.y + sx[c + 2] * wv.z + sx[c + 3] * wv.w;
  }
  const float hn =
      (acc - rmean[j]) * rsqrtf(rvar[j] + 1e-5f) * gamma[j] + beta[j];
  const float sp = (hn > 20.f) ? hn : log1pf(expf(hn));
  out[b * kH + j] = hn * tanhf(sp) + res[b * kH + j];
}

// ---------------------------------------------------------------------------
extern "C" void kernel_launch(void* const* d_in, const int* in_sizes, int n_in,
                              void* d_out, int out_size, void* d_ws,
                              size_t ws_size, hipStream_t stream) {
  const float* q = (const float*)d_in[0];
  const float* k = (const float*)d_in[1];
  const float* v = (const float*)d_in[2];
  const float* attn_bias = (const float*)d_in[3];
  const float* W_Q = (const float*)d_in[4];
  const float* W_K = (const float*)d_in[5];
  const float* W_V = (const float*)d_in[6];
  const float* W1 = (const float*)d_in[7];
  const float* b1 = (const float*)d_in[8];
  const float* gamma = (const float*)d_in[9];
  const float* beta = (const float*)d_in[10];
  const float* rmean = (const float*)d_in[11];
  const float* rvar = (const float*)d_in[12];

  char* ws = (char*)d_ws;
  unsigned short* Qbf = (unsigned short*)(ws + OFF_QBF);
  unsigned short* Kbf = (unsigned short*)(ws + OFF_KBF);
  unsigned short* Vbf = (unsigned short*)(ws + OFF_VBF);
  unsigned short* biasbf = (unsigned short*)(ws + OFF_BIAS);
  float* colw = (float*)(ws + OFF_COLW);
  float* res = (float*)(ws + OFF_RES);
  float* xs = (float*)(ws + OFF_XS);

  float* out = (float*)d_out;
  float* attn_out = out + (size_t)kB * kH;  // attention starts at +4096

  // zero colw + res accumulators (contiguous)
  hipMemsetAsync(ws + OFF_COLW, 0, SZ_COLW + SZ_RES, stream);

  proj_kernel<<<dim3(kM / 64, kH / 64, 3), 256, 0, stream>>>(
      q, k, v, W_Q, W_K, W_V, Qbf, Kbf, Vbf);
  bias_conv_kernel<<<(kNH * kS * kS) / (256 * 4), 256, 0, stream>>>(attn_bias,
                                                                    biasbf);
  res_sum_kernel<<<kB * 8, 256, 0, stream>>>(q, res);
  attn_kernel<<<dim3(kB, kS / 64, kNH), 256, 0, stream>>>(Qbf, Kbf, biasbf,
                                                          attn_out, colw);
  xs_kernel<<<kB * kNH, 256, 0, stream>>>(colw, Vbf, xs);
  final_kernel<<<kB, 256, 0, stream>>>(xs, res, W1, b1, gamma, beta, rmean,
                                       rvar, out);
}